// Round 14
// baseline (692.764 us; speedup 1.0000x reference)
//
#include <hip/hip_runtime.h>
#include <hip/hip_bf16.h>
#include <math.h>

// Memory module: E=768, S=128, T=3, B=64, L=512. fp32 in/out.
// bf16 MFMA GEMMs (fp32 accum). Folds: Fqk=Wq^T Wk, Fwv=Wo Wv, Fvo=Ro Rv, Frq=Rq^T Rk.
// gemm_nt64p: 128x128 tile, BK=64, double-buffered LDS (64KB), counted vmcnt(8)
// (no mid-loop drain), both-sides XOR swizzle, hoisted loop-invariant addresses.
// d_out doubles as scratch: ghb at +0, zb at +48MB; final GEMM overwrites d_out last.

typedef __attribute__((ext_vector_type(4))) float f32x4;
typedef __attribute__((ext_vector_type(8))) short short8;
typedef __attribute__((ext_vector_type(4))) unsigned short us4;

__device__ __forceinline__ unsigned short f2bf(float x) {
  union { float f; unsigned u; } v; v.f = x;
  unsigned r = v.u + 0x7fffu + ((v.u >> 16) & 1u);  // RNE
  return (unsigned short)(r >> 16);
}
__device__ __forceinline__ float bf2f(unsigned short u) {
  union { unsigned u; float f; } v; v.u = (unsigned)u << 16; return v.f;
}

__device__ __forceinline__ void g2l16(const void* g, void* l) {
  __builtin_amdgcn_global_load_lds(
      (const __attribute__((address_space(1))) unsigned int*)g,
      (__attribute__((address_space(3))) unsigned int*)l, 16, 0, 0);
}

__device__ __forceinline__ float wsum(float v) {
#pragma unroll
  for (int o = 32; o > 0; o >>= 1) v += __shfl_xor(v, o, 64);
  return v;
}
__device__ __forceinline__ float wmax(float v) {
#pragma unroll
  for (int o = 32; o > 0; o >>= 1) v = fmaxf(v, __shfl_xor(v, o, 64));
  return v;
}

// m204 bijective XCD swizzle of flattened grid -> (tn, tm, bz)
__device__ __forceinline__ void xcd_map(int& tn, int& tm, long long& bz) {
  const int gx = gridDim.x, gy = gridDim.y, gz = gridDim.z;
  const int nwg = gx * gy * gz;
  const int lin = blockIdx.x + gx * (blockIdx.y + gy * blockIdx.z);
  const int q = nwg >> 3, r = nwg & 7;
  const int xcd = lin & 7, jj = lin >> 3;
  const int w = (xcd < r ? xcd * (q + 1) : r * (q + 1) + (xcd - r) * q) + jj;
  tn = w % gx;
  const int t2 = w / gx;
  tm = t2 % gy;
  bz = t2 / gy;
}

__device__ __forceinline__ void c_write_128(
    void* Cg, size_t cb, int N, int tm, int tn, int wr, int wc, int lane,
    const f32x4 acc[4][4], const float* bias, bool has_bias, float alpha, int omode)
{
#pragma unroll
  for (int a = 0; a < 4; ++a) {
    const int row0 = tm * 128 + wr * 64 + a * 16 + (lane >> 4) * 4;
#pragma unroll
    for (int b = 0; b < 4; ++b) {
      const int col = tn * 128 + wc * 64 + b * 16 + (lane & 15);
      float bv = has_bias ? bias[col] : 0.f;
#pragma unroll
      for (int rr = 0; rr < 4; ++rr) {
        float v = acc[a][b][rr] * alpha + bv;
        if (omode == 0)
          ((float*)Cg)[cb + (size_t)(row0 + rr) * N + col] = v;
        else
          ((unsigned short*)Cg)[cb + (size_t)(row0 + rr) * N + col] = f2bf(v);
      }
    }
  }
}

// ---- m97 128x128 BK=32 body (fold quad only) ----
template<int OMODE, bool BIAS>
__device__ __forceinline__ void gemm_body(
    const unsigned short* __restrict__ A, const unsigned short* __restrict__ B,
    const float* __restrict__ bias, void* __restrict__ Cg, size_t cb,
    int N, int K, int tm, int tn, float alpha,
    unsigned short* As, unsigned short* Bs)
{
  const int tid  = threadIdx.x;
  const int lane = tid & 63;
  const int wv   = tid >> 6;
  const int wr   = wv >> 1, wc = wv & 1;

  A += (size_t)tm * 128 * K;
  B += (size_t)tn * 128 * K;

  const int srow = wv * 16 + (lane >> 2);
  const int kby  = (lane & 3) * 16;

  f32x4 acc[4][4];
#pragma unroll
  for (int a = 0; a < 4; ++a)
#pragma unroll
    for (int b = 0; b < 4; ++b) acc[a][b] = (f32x4)(0.f);

  const int mrow = wr * 64 + (lane & 15);
  const int nrow = wc * 64 + (lane & 15);
  const int koff = (lane >> 4) * 8;

  for (int kt = 0; kt < K; kt += 32) {
#pragma unroll
    for (int i = 0; i < 2; ++i) {
      g2l16((const char*)(A + (size_t)(i * 64 + srow) * K + kt) + kby,
            (char*)As + i * 4096 + wv * 1024);
      g2l16((const char*)(B + (size_t)(i * 64 + srow) * K + kt) + kby,
            (char*)Bs + i * 4096 + wv * 1024);
    }
    __syncthreads();
    short8 af[4], bf[4];
#pragma unroll
    for (int a = 0; a < 4; ++a) af[a] = *(const short8*)&As[(mrow + a * 16) * 32 + koff];
#pragma unroll
    for (int b = 0; b < 4; ++b) bf[b] = *(const short8*)&Bs[(nrow + b * 16) * 32 + koff];
#pragma unroll
    for (int a = 0; a < 4; ++a)
#pragma unroll
      for (int b = 0; b < 4; ++b)
        acc[a][b] = __builtin_amdgcn_mfma_f32_16x16x32_bf16(af[a], bf[b], acc[a][b], 0, 0, 0);
    __syncthreads();
  }
  c_write_128(Cg, cb, N, tm, tn, wr, wc, lane, acc, bias, BIAS, alpha, OMODE);
}

// ---- BK=64, double-buffered, counted-vmcnt pipelined 128x128 NT GEMM ----
// LDS 64KB (2 buf x 16KB x 2 operands). Per tile: wait vmcnt(8) -> barrier ->
// compute (hoisted swizzled offsets) -> barrier -> stage tile u+2 into freed buf.
// No mid-loop vmcnt(0) drain. Requires K%64==0 (nt>=2), M%128==0, N%128==0.
template<int OMODE, bool BIAS>
__global__ __launch_bounds__(256) void gemm_nt64p(
    const unsigned short* __restrict__ Ag, const unsigned short* __restrict__ Bg,
    const float* __restrict__ bias, void* __restrict__ Cg,
    int M, int N, int K, long long sA, long long sB, long long sC,
    long long sBias, float alpha)
{
  __shared__ __align__(16) unsigned short As[2][128 * 64];  // 2 x 16KB
  __shared__ __align__(16) unsigned short Bs[2][128 * 64];

  const int tid  = threadIdx.x;
  const int lane = tid & 63;
  const int wv   = tid >> 6;
  const int wr   = wv >> 1, wc = wv & 1;

  int tn, tm; long long bz;
  xcd_map(tn, tm, bz);

  const unsigned short* A = Ag + bz * sA + (size_t)tm * 128 * K;
  const unsigned short* B = Bg + bz * sB + (size_t)tn * 128 * K;

  auto swz = [](int o) { return o ^ (((o >> 7) & 7) << 4); };

  // hoisted staging source pointers (pre-swizzled global coords)
  const char* aSrc[4];
  const char* bSrc[4];
#pragma unroll
  for (int c = 0; c < 4; ++c) {
    const int olog = swz(c * 4096 + tid * 16);
    const int row = olog >> 7, cbyte = olog & 127;
    aSrc[c] = (const char*)(A + (size_t)row * K) + cbyte;
    bSrc[c] = (const char*)(B + (size_t)row * K) + cbyte;
  }
  // hoisted LDS read byte-offsets
  const int mrow = wr * 64 + (lane & 15);
  const int nrow = wc * 64 + (lane & 15);
  const int kb   = (lane >> 4) * 16;
  int aoff[4][2], boff[4][2];
#pragma unroll
  for (int a = 0; a < 4; ++a)
#pragma unroll
    for (int h = 0; h < 2; ++h) {
      aoff[a][h] = swz((mrow + a * 16) * 128 + h * 64 + kb);
      boff[a][h] = swz((nrow + a * 16) * 128 + h * 64 + kb);
    }

  auto stage = [&](int bi, size_t ktB) {
#pragma unroll
    for (int c = 0; c < 4; ++c) {
      g2l16(aSrc[c] + ktB, (char*)As[bi] + c * 4096 + wv * 1024);
      g2l16(bSrc[c] + ktB, (char*)Bs[bi] + c * 4096 + wv * 1024);
    }
  };

  f32x4 acc[4][4];
#pragma unroll
  for (int a = 0; a < 4; ++a)
#pragma unroll
    for (int b = 0; b < 4; ++b) acc[a][b] = (f32x4)(0.f);

  const int nt = K >> 6;
  stage(0, 0);
  stage(1, 128);

  for (int u = 0; u < nt; ++u) {
    if (u + 1 < nt) asm volatile("s_waitcnt vmcnt(8)" ::: "memory");
    else            asm volatile("s_waitcnt vmcnt(0)" ::: "memory");
    __builtin_amdgcn_s_barrier();          // all waves' tile-u DMA landed
    __builtin_amdgcn_sched_barrier(0);
    const char* Ab = (const char*)As[u & 1];
    const char* Bb = (const char*)Bs[u & 1];
#pragma unroll
    for (int h = 0; h < 2; ++h) {
      short8 af[4], bf[4];
#pragma unroll
      for (int a = 0; a < 4; ++a) af[a] = *(const short8*)(Ab + aoff[a][h]);
#pragma unroll
      for (int b = 0; b < 4; ++b) bf[b] = *(const short8*)(Bb + boff[b][h]);
#pragma unroll
      for (int a = 0; a < 4; ++a)
#pragma unroll
        for (int b = 0; b < 4; ++b)
          acc[a][b] = __builtin_amdgcn_mfma_f32_16x16x32_bf16(af[a], bf[b], acc[a][b], 0, 0, 0);
    }
    __builtin_amdgcn_sched_barrier(0);
    __builtin_amdgcn_s_barrier();          // all waves done reading buf[u&1]
    if (u + 2 < nt) stage(u & 1, (size_t)(u + 2) * 128);
  }

  const float* bp = BIAS ? bias + bz * sBias : (const float*)nullptr;
  c_write_128(Cg, (size_t)(bz * sC), N, tm, tn, wr, wc, lane, acc, bp, BIAS, alpha, OMODE);
}

// 4 independent 768^3 NT GEMMs (fold products). bf16 out, no bias.
struct QuadPtrs {
  const unsigned short* a[4];
  const unsigned short* b[4];
  unsigned short* c[4];
};
__global__ __launch_bounds__(256) void gemm_nt_quad(QuadPtrs p) {
  __shared__ __align__(16) unsigned short As[128 * 32];
  __shared__ __align__(16) unsigned short Bs[128 * 32];
  const int zi = blockIdx.z;
  gemm_body<1, false>(p.a[zi], p.b[zi], nullptr, (void*)p.c[zi], 0,
                      768, 768, blockIdx.y, blockIdx.x, 1.0f, As, Bs);
}

// Softmax LR=512: float4 loads, us4 stores. One wave per row.
__global__ __launch_bounds__(256) void softmax512(
    const float* __restrict__ sc, unsigned short* __restrict__ p)
{
  const int row  = blockIdx.x * 4 + (threadIdx.x >> 6);
  const int lane = threadIdx.x & 63;
  const float4* sr = (const float4*)(sc + (size_t)row * 512);
  float4 v[2];
  float m = -1e30f;
#pragma unroll
  for (int j = 0; j < 2; ++j) {
    v[j] = sr[lane + 64 * j];
    m = fmaxf(m, fmaxf(fmaxf(v[j].x, v[j].y), fmaxf(v[j].z, v[j].w)));
  }
  m = wmax(m);
  float s = 0.f;
#pragma unroll
  for (int j = 0; j < 2; ++j) {
    v[j].x = __expf(v[j].x - m); v[j].y = __expf(v[j].y - m);
    v[j].z = __expf(v[j].z - m); v[j].w = __expf(v[j].w - m);
    s += v[j].x + v[j].y + v[j].z + v[j].w;
  }
  s = wsum(s);
  const float inv = 1.f / s;
  us4* pr = (us4*)(p + (size_t)row * 512);
#pragma unroll
  for (int j = 0; j < 2; ++j) {
    us4 o;
    o.x = f2bf(v[j].x * inv); o.y = f2bf(v[j].y * inv);
    o.z = f2bf(v[j].z * inv); o.w = f2bf(v[j].w * inv);
    pr[lane + 64 * j] = o;
  }
}

// Softmax LR=128. One wave per row.
__global__ __launch_bounds__(256) void softmax128(
    const float* __restrict__ sc, unsigned short* __restrict__ p)
{
  const int row  = blockIdx.x * 4 + (threadIdx.x >> 6);
  const int lane = threadIdx.x & 63;
  const float* sr = sc + (size_t)row * 128;
  float v[2];
  float m = -1e30f;
#pragma unroll
  for (int j = 0; j < 2; ++j) { v[j] = sr[lane + 64 * j]; m = fmaxf(m, v[j]); }
  m = wmax(m);
  float s = 0.f;
#pragma unroll
  for (int j = 0; j < 2; ++j) { v[j] = __expf(v[j] - m); s += v[j]; }
  s = wsum(s);
  const float inv = 1.f / s;
  unsigned short* pr = p + (size_t)row * 128;
#pragma unroll
  for (int j = 0; j < 2; ++j) pr[lane + 64 * j] = f2bf(v[j] * inv);
}

// GRU combine with inline LN of old mem (h) + emit next operand.
template<bool GHB, bool EMITLN>
__global__ __launch_bounds__(256) void gru_ln_combine(
    const unsigned short* __restrict__ gi, const unsigned short* __restrict__ gh,
    float* __restrict__ mem, const float* __restrict__ g, const float* __restrict__ b,
    unsigned short* __restrict__ outb)
{
  __shared__ float ps[4], pq[4];
  const size_t row = blockIdx.x;
  const int tid = threadIdx.x, wv = tid >> 6, lane = tid & 63;
  float* mr = mem + row * 768;
  const size_t ghrow = GHB ? (row & 127) : row;
  float v[3];
  float s = 0.f, q = 0.f;
#pragma unroll
  for (int k = 0; k < 3; ++k) {
    v[k] = mr[tid + 256 * k];
    s += v[k]; q += v[k] * v[k];
  }
  s = wsum(s); q = wsum(q);
  if (lane == 0) { ps[wv] = s; pq[wv] = q; }
  __syncthreads();
  s = ps[0] + ps[1] + ps[2] + ps[3];
  q = pq[0] + pq[1] + pq[2] + pq[3];
  const float mu = s * (1.f / 768.f);
  const float rstd = rsqrtf(q * (1.f / 768.f) - mu * mu + 1e-5f);
  float nv[3];
  float s2 = 0.f, q2 = 0.f;
#pragma unroll
  for (int k = 0; k < 3; ++k) {
    const int c = tid + 256 * k;
    const float h = (v[k] - mu) * rstd * g[c] + b[c];
    const float ir  = bf2f(gi[row * 2304 + c]);
    const float iz  = bf2f(gi[row * 2304 + 768 + c]);
    const float in_ = bf2f(gi[row * 2304 + 1536 + c]);
    const float hr  = bf2f(gh[ghrow * 2304 + c]);
    const float hz  = bf2f(gh[ghrow * 2304 + 768 + c]);
    const float hn  = bf2f(gh[ghrow * 2304 + 1536 + c]);
    const float rg = 1.f / (1.f + __expf(-(ir + hr)));
    const float zg = 1.f / (1.f + __expf(-(iz + hz)));
    const float n  = tanhf(in_ + rg * hn);
    nv[k] = (1.f - zg) * n + zg * h;
    mr[c] = nv[k];
    s2 += nv[k]; q2 += nv[k] * nv[k];
  }
  if (EMITLN) {
    s2 = wsum(s2); q2 = wsum(q2);
    __syncthreads();
    if (lane == 0) { ps[wv] = s2; pq[wv] = q2; }
    __syncthreads();
    s2 = ps[0] + ps[1] + ps[2] + ps[3];
    q2 = pq[0] + pq[1] + pq[2] + pq[3];
    const float mu2 = s2 * (1.f / 768.f);
    const float rstd2 = rsqrtf(q2 * (1.f / 768.f) - mu2 * mu2 + 1e-5f);
#pragma unroll
    for (int k = 0; k < 3; ++k) {
      const int c = tid + 256 * k;
      outb[row * 768 + c] = f2bf((nv[k] - mu2) * rstd2 * g[c] + b[c]);
    }
  } else {
#pragma unroll
    for (int k = 0; k < 3; ++k) {
      const int c = tid + 256 * k;
      outb[row * 768 + c] = f2bf(nv[k]);
    }
  }
}

// Merged weight conversion: 10 fp32 sources -> contiguous bf16 region.
__global__ __launch_bounds__(256) void cvt_weights(
    const float* p0, const float* p1, const float* p2, const float* p3,
    const float* p4, const float* p5, const float* p6, const float* p7,
    const float* p8, const float* p9, unsigned short* __restrict__ dst)
{
  const int i = blockIdx.x * 256 + threadIdx.x;  // f4 index, total 2064384
  if (i >= 2064384) return;
  const float* src; int base;
  if      (i < 147456)  { src = p0; base = 0; }
  else if (i < 294912)  { src = p1; base = 147456; }
  else if (i < 442368)  { src = p2; base = 294912; }
  else if (i < 589824)  { src = p3; base = 442368; }
  else if (i < 737280)  { src = p4; base = 589824; }
  else if (i < 884736)  { src = p5; base = 737280; }
  else if (i < 1032192) { src = p6; base = 884736; }
  else if (i < 1179648) { src = p7; base = 1032192; }
  else if (i < 1622016) { src = p8; base = 1179648; }
  else                  { src = p9; base = 1622016; }
  const float4 v = ((const float4*)src)[i - base];
  us4 o;
  o.x = f2bf(v.x); o.y = f2bf(v.y); o.z = f2bf(v.z); o.w = f2bf(v.w);
  ((us4*)dst)[i] = o;
}

// memf[b,s,:] = slots[s,:]; memb[b,s,:] = bf16(LN(slots[s,:])). Grid (128, 8).
__global__ __launch_bounds__(256) void init_mem(
    const float* __restrict__ slots, const float* __restrict__ g,
    const float* __restrict__ b, float* __restrict__ memf,
    unsigned short* __restrict__ memb)
{
  __shared__ float ps[4], pq[4];
  const int s = blockIdx.x;
  const int g0 = blockIdx.y * 8;
  const int tid = threadIdx.x, wv = tid >> 6, lane = tid & 63;
  const float* sr = slots + (size_t)s * 768;
  float v[3];
  float su = 0.f, qu = 0.f;
#pragma unroll
  for (int k = 0; k < 3; ++k) { v[k] = sr[tid + 256 * k]; su += v[k]; qu += v[k] * v[k]; }
  su = wsum(su); qu = wsum(qu);
  if (lane == 0) { ps[wv] = su; pq[wv] = qu; }
  __syncthreads();
  su = ps[0] + ps[1] + ps[2] + ps[3];
  qu = pq[0] + pq[1] + pq[2] + pq[3];
  const float mu = su * (1.f / 768.f);
  const float rstd = rsqrtf(qu * (1.f / 768.f) - mu * mu + 1e-5f);
  unsigned short lb[3];
#pragma unroll
  for (int k = 0; k < 3; ++k) {
    const int c = tid + 256 * k;
    lb[k] = f2bf((v[k] - mu) * rstd * g[c] + b[c]);
  }
  for (int bb = g0; bb < g0 + 8; ++bb) {
    float* mrow = memf + ((size_t)bb * 128 + s) * 768;
    unsigned short* brow = memb + ((size_t)bb * 128 + s) * 768;
#pragma unroll
    for (int k = 0; k < 3; ++k) { mrow[tid + 256 * k] = v[k]; brow[tid + 256 * k] = lb[k]; }
  }
}

// 6 independent 768x768 transposes in one launch (weight prologue only).
struct TPtrs { const unsigned short* s[6]; unsigned short* d[6]; };
__global__ void transpose_multi(TPtrs p) {
  __shared__ unsigned short t[32][33];
  const unsigned short* in = p.s[blockIdx.z];
  unsigned short* out = p.d[blockIdx.z];
  const int c0 = blockIdx.x * 32, r0 = blockIdx.y * 32;
  const int x = threadIdx.x, y = threadIdx.y;
#pragma unroll
  for (int k = 0; k < 32; k += 8)
    t[y + k][x] = in[(size_t)(r0 + y + k) * 768 + c0 + x];
  __syncthreads();
#pragma unroll
  for (int k = 0; k < 32; k += 8)
    out[(size_t)(c0 + y + k) * 768 + r0 + x] = t[x][y + k];
}

// Two y[row] = dot(Tmat[row,:], x) jobs over bf16 row-major mats (wave per row).
__global__ __launch_bounds__(256) void matvec_row2b(
    const unsigned short* __restrict__ A0, const float* __restrict__ x0,
    float* __restrict__ y0,
    const unsigned short* __restrict__ A1, const float* __restrict__ x1,
    float* __restrict__ y1)
{
  const int task = blockIdx.x / 192;
  const int row = (blockIdx.x % 192) * 4 + (threadIdx.x >> 6);
  const int lane = threadIdx.x & 63;
  const unsigned short* r = (task ? A1 : A0) + (size_t)row * 768;
  const float* x = task ? x1 : x0;
  float s = 0.f;
#pragma unroll
  for (int j = 0; j < 12; ++j) s += bf2f(r[lane + 64 * j]) * x[lane + 64 * j];
  s = wsum(s);
  if (lane == 0) (task ? y1 : y0)[row] = s;
}

// Two y[row]=add[row]+dot(W[row,:],x) fp32 jobs (grid 384: task = bx/192).
__global__ __launch_bounds__(256) void matvec_row2(
    const float* __restrict__ W0, const float* __restrict__ x0,
    const float* __restrict__ a0, float* __restrict__ y0,
    const float* __restrict__ W1, const float* __restrict__ x1,
    const float* __restrict__ a1, float* __restrict__ y1)
{
  const int task = blockIdx.x / 192;
  const int row = (blockIdx.x % 192) * 4 + (threadIdx.x >> 6);
  const int lane = threadIdx.x & 63;
  const float* W = task ? W1 : W0;
  const float* x = task ? x1 : x0;
  const float* ad = task ? a1 : a0;
  float* y = task ? y1 : y0;
  const float4* r = (const float4*)(W + (size_t)row * 768);
  const float4* xv = (const float4*)x;
  float s = 0.f;
#pragma unroll
  for (int j = 0; j < 3; ++j) {
    const float4 a = r[lane + 64 * j], c = xv[lane + 64 * j];
    s += a.x * c.x + a.y * c.y + a.z * c.z + a.w * c.w;
  }
  s = wsum(s);
  if (lane == 0) y[row] = s + ad[row];
}

// out[i] = scl * (dot(src_i, vec) + (cadd ? cadd[0] : 0)). float4 loads.
__global__ __launch_bounds__(256) void rowdot768(
    const float* __restrict__ src, const float* __restrict__ vec,
    const float* __restrict__ cadd, float* __restrict__ out, float scl, int rows)
{
  const int row  = blockIdx.x * 4 + (threadIdx.x >> 6);
  if (row >= rows) return;
  const int lane = threadIdx.x & 63;
  const float4* r = (const float4*)(src + (size_t)row * 768);
  const float4* vv = (const float4*)vec;
  float s = 0.f;
#pragma unroll
  for (int j = 0; j < 3; ++j) {
    const float4 a = r[lane + 64 * j], c = vv[lane + 64 * j];
    s += a.x * c.x + a.y * c.y + a.z * c.z + a.w * c.w;
  }
  s = wsum(s);
  if (lane == 0) out[row] = scl * (s + (cadd ? cadd[0] : 0.f));
}

// Fused: zb = bf16(z) AND zv[row] = scl*(dot(z_row, vw) + cw[0]). float4 loads.
__global__ __launch_bounds__(256) void cvt_z_zv(
    const float* __restrict__ z, unsigned short* __restrict__ zb,
    const float* __restrict__ vw, const float* __restrict__ cw,
    float* __restrict__ zv, float scl)
{
  const int row = blockIdx.x * 4 + (threadIdx.x >> 6);
  const int lane = threadIdx.x & 63;
  const float4* zr = (const float4*)(z + (size_t)row * 768);
  const float4* wv = (const float4*)vw;
  us4* zbr = (us4*)(zb + (size_t)row * 768);
  float s = 0.f;
#pragma unroll
  for (int j = 0; j < 3; ++j) {
    const float4 v = zr[lane + 64 * j];
    const float4 w = wv[lane + 64 * j];
    s += v.x * w.x + v.y * w.y + v.z * w.z + v.w * w.w;
    us4 o;
    o.x = f2bf(v.x); o.y = f2bf(v.y); o.z = f2bf(v.z); o.w = f2bf(v.w);
    zbr[lane + 64 * j] = o;
  }
  s = wsum(s);
  if (lane == 0) zv[row] = scl * (s + cw[0]);
}

__global__ __launch_bounds__(256) void diag_ws(float* __restrict__ out, float wsz, int n) {
  const int i = blockIdx.x * 256 + threadIdx.x;
  if (i < n) out[i] = (i == 0) ? wsz : 0.f;
}

extern "C" void kernel_launch(void* const* d_in, const int* in_sizes, int n_in,
                              void* d_out, int out_size, void* d_ws, size_t ws_size,
                              hipStream_t stream)
{
  const float* z     = (const float*)d_in[0];
  const float* slots = (const float*)d_in[1];
  const float* ln_g  = (const float*)d_in[2];
  const float* ln_b  = (const float*)d_in[3];
  const float* w_wq = (const float*)d_in[4];  const float* w_bq = (const float*)d_in[5];
  const float* w_wk = (const float*)d_in[6];  const float* w_bk = (const float*)d_in[7];
  const float* w_wv = (const float*)d_in[8];  const float* w_bv = (const float*)d_in[9];
  const float* w_wo = (const float*)d_in[10]; const float* w_bo = (const float*)d_in[11];
  const float* r_wq = (const float*)d_in[12]; const float* r_bq = (const float*)d_in[13];
  const float* r_wk = (const float*)d_in[14]; const float* r_bk = (const float*)d_in[15];
  const float* r_wv = (const float*)d_in[16]; const float* r_bv = (const float*)d_in[17];
  const float* r_wo = (const float*)d_in[18]; const float* r_bo = (const float*)d_in[19];
  const float* g_wih = (const float*)d_in[20]; const float* g_bih = (const float*)d_in[21];
  const float* g_whh = (const float*)d_in[22]; const float* g_bhh = (const float*)d_in[23];

  // ---- arena (bytes) ----
  constexpr size_t O_F    = 16515072;
  constexpr size_t O_T6   = 21233664;
  constexpr size_t O_GH0  = 28311552;
  constexpr size_t O_FL   = 28901376;
  constexpr size_t O_memf = 29096192;
  constexpr size_t O_Kz   = 54262016;
  constexpr size_t O_VwoT = 104593664;
  constexpr size_t O_L    = 154925312;
  constexpr size_t NEED   = 217839872;

  if (ws_size < NEED) {
    hipLaunchKernelGGL(diag_ws, dim3((out_size + 255) / 256), dim3(256), 0, stream,
                       (float*)d_out, (float)ws_size, out_size);
    return;
  }

  char* ws = (char*)d_ws;
  unsigned short* wqb  = (unsigned short*)(ws + 0);
  unsigned short* wkb  = wqb + 589824;
  unsigned short* wvb  = wkb + 589824;
  unsigned short* wob  = wvb + 589824;
  unsigned short* rqb  = wob + 589824;
  unsigned short* rkb  = rqb + 589824;
  unsigned short* rvb  = rkb + 589824;
  unsigned short* rob  = rvb + 589824;
  unsigned short* wihb = rob + 589824;
  unsigned short* whhb = wihb + 1769472;
  unsigned short* Fqk  = (unsigned short*)(ws + O_F);
  unsigned short* Fwv  = Fqk + 589824;
  unsigned short* Fvo  = Fwv + 589824;
  unsigned short* Frq  = Fvo + 589824;
  unsigned short* T0   = (unsigned short*)(ws + O_T6);
  unsigned short* T1   = T0 + 589824;
  unsigned short* T2   = T1 + 589824;
  unsigned short* T3   = T2 + 589824;
  unsigned short* T4   = T3 + 589824;
  unsigned short* T5   = T4 + 589824;
  unsigned short* gh0  = (unsigned short*)(ws + O_GH0);
  float* bih_c   = (float*)(ws + O_FL);
  float* bhh_c   = bih_c + 2304;
  float* const_o = bhh_c + 2304;
  float* bvo     = const_o + 768;
  float* vw      = bvo + 768;
  float* vr      = vw + 768;
  float* cw      = vr + 768;
  float* zv      = cw + 64;
  float* colb    = zv + 32768;
  float* memf = (float*)(ws + O_memf);
  unsigned short* Kz    = (unsigned short*)(ws + O_Kz);
  unsigned short* memFr = (unsigned short*)(ws + O_Kz);            // end (Kz dead)
  unsigned short* VwoT  = (unsigned short*)(ws + O_VwoT);
  unsigned short* memVoT  = (unsigned short*)(ws + O_VwoT);             // end
  float*          Sbr     = (float*)(ws + O_VwoT + 25165824);           // end
  unsigned short* Abr     = (unsigned short*)(ws + O_VwoT + 41943040);  // end
  char* L = ws + O_L;
  unsigned short* memb  = (unsigned short*)(L + 0);
  unsigned short* updb  = (unsigned short*)(L + 12582912);
  float*          Sbuf  = (float*)(L + 25165824);
  unsigned short* Abuf  = (unsigned short*)(L + 41943040);
  unsigned short* gib   = (unsigned short*)(L + 25165824);   // (S/A dead)
  unsigned short* ghb   = (unsigned short*)d_out;
  unsigned short* zb    = (unsigned short*)((char*)d_out + 50331648);

  const float scale = 1.0f / sqrtf(768.f);

  // ---- prologue ----
  hipLaunchKernelGGL(cvt_weights, dim3(8064), dim3(256), 0, stream,
      w_wq, w_wk, w_wv, w_wo, r_wq, r_wk, r_wv, r_wo, g_wih, g_whh, wqb);
  hipMemcpyAsync(bih_c, g_bih, 2304 * 4, hipMemcpyDeviceToDevice, stream);
  hipMemcpyAsync(bhh_c, g_bhh, 2304 * 4, hipMemcpyDeviceToDevice, stream);

  {
    TPtrs tp;
    tp.s[0] = wqb; tp.d[0] = T0;
    tp.s[1] = wkb; tp.d[1] = T1;
    tp.s[2] = wvb; tp.d[2] = T2;
    tp.s[3] = rvb; tp.d[3] = T3;
    tp.s[4] = rqb; tp.d[4] = T4;
    tp.s[5] = rkb; tp.d[5] = T5;
    hipLaunchKernelGGL(transpose_multi, dim3(24, 24, 6), dim3(32, 8), 0, stream, tp);
  }
  {
    QuadPtrs qp;
    qp.a[0] = T0;  qp.b[0] = T1; qp.c[0] = Fqk;
    qp.a[1] = wob; qp.b[1] = T2; qp.c[1] = Fwv;
    qp.a[2] = rob; qp.b[2] = T3; qp.c[2] = Fvo;
    qp.a[3] = T4;  qp.b[3] = T5; qp.c[3] = Frq;
    hipLaunchKernelGGL(gemm_nt_quad, dim3(6, 6, 4), dim3(256), 0, stream, qp);
  }

  hipLaunchKernelGGL(matvec_row2b, dim3(384), dim3(256), 0, stream,
      T1, w_bq, vw, T5, r_bq, vr);
  hipLaunchKernelGGL(matvec_row2, dim3(384), dim3(256), 0, stream,
      w_wo, w_bv, w_bo, const_o, r_wo, r_bv, r_bo, bvo);
  hipLaunchKernelGGL(rowdot768, dim3(1), dim3(256), 0, stream,
      w_bq, w_bk, (const float*)nullptr, cw, 1.0f, 1);
  hipLaunchKernelGGL(cvt_z_zv, dim3(8192), dim3(256), 0, stream, z, zb, vw, cw, zv, scale);
  hipLaunchKernelGGL(init_mem, dim3(128, 8), dim3(256), 0, stream,
      slots, ln_g, ln_b, memf, memb);

  // VwoT[b] = Fwv . z_b^T ; Kz = z . Fqk^T
  hipLaunchKernelGGL((gemm_nt64p<1, false>), dim3(4, 6, 64), dim3(256), 0, stream,
      Fwv, zb, (const float*)nullptr, (void*)VwoT, 768, 512, 768,
      0ll, 393216ll, 393216ll, 0ll, 1.0f);
  hipLaunchKernelGGL((gemm_nt64p<1, false>), dim3(6, 256, 1), dim3(256), 0, stream,
      zb, Fqk, (const float*)nullptr, (void*)Kz, 32768, 768, 768, 0ll, 0ll, 0ll, 0ll, 1.0f);

  const long long sA_g = (long long)(memb - updb);
  const long long sC_g = (long long)(ghb - gib);

  // ---- T=3 recurrence ----
  for (int t = 0; t < 3; ++t) {
    hipLaunchKernelGGL((gemm_nt64p<0, true>), dim3(4, 1, 64), dim3(256), 0, stream,
        memb, Kz, zv, (void*)Sbuf, 128, 512, 768,
        98304ll, 393216ll, 65536ll, 512ll, scale);
    hipLaunchKernelGGL(softmax512, dim3(2048), dim3(256), 0, stream, Sbuf, Abuf);
    hipLaunchKernelGGL((gemm_nt64p<1, true>), dim3(6, 1, 64), dim3(256), 0, stream,
        Abuf, VwoT, const_o, (void*)updb, 128, 768, 512,
        65536ll, 393216ll, 98304ll, 0ll, 1.0f);
    if (t == 0) {
      hipLaunchKernelGGL((gemm_nt64p<1, true>), dim3(18, 1, 1), dim3(256), 0, stream,
          memb, whhb, bhh_c, (void*)gh0, 128, 2304, 768, 0ll, 0ll, 0ll, 0ll, 1.0f);
      hipLaunchKernelGGL((gemm_nt64p<1, true>), dim3(18, 64, 1), dim3(256), 0, stream,
          updb, wihb, bih_c, (void*)gib, 8192, 2304, 768, 0ll, 0ll, 0ll, 0ll, 1.0f);
      hipLaunchKernelGGL((gru_ln_combine<true, true>), dim3(8192), dim3(256), 0, stream,
          gib, gh0, memf, ln_g, ln_b, memb);
    } else {
      hipLaunchKernelGGL((gemm_nt64p<1, true>), dim3(18, 64, 2), dim3(256), 0, stream,
          updb, wihb, bih_c, (void*)gib, 8192, 2304, 768,
          sA_g, 1769472ll, sC_g, 2304ll, 1.0f);
      if (t < 2)
        hipLaunchKernelGGL((gru_ln_combine<false, true>), dim3(8192), dim3(256), 0, stream,
            gib, ghb, memf, ln_g, ln_b, memb);
      else
        hipLaunchKernelGGL((gru_ln_combine<false, false>), dim3(8192), dim3(256), 0, stream,
            gib, ghb, memf, ln_g, ln_b, memb);
    }
  }
  // memb now holds bf16(mem_final)

  // ---- read attention ----
  hipLaunchKernelGGL((gemm_nt64p<1, false>), dim3(6, 64, 1), dim3(256), 0, stream,
      memb, Frq, (const float*)nullptr, (void*)memFr, 8192, 768, 768,
      0ll, 0ll, 0ll, 0ll, 1.0f);
  hipLaunchKernelGGL((gemm_nt64p<1, false>), dim3(1, 6, 64), dim3(256), 0, stream,
      Fvo, memb, (const float*)nullptr, (void*)memVoT, 768, 128, 768,
      0ll, 98304ll, 98304ll, 0ll, 1.0f);
  hipLaunchKernelGGL(rowdot768, dim3(2048), dim3(256), 0, stream,
      memf, vr, (const float*)nullptr, colb, scale, 8192);
  hipLaunchKernelGGL((gemm_nt64p<0, true>), dim3(1, 4, 64), dim3(256), 0, stream,
      zb, memFr, colb, (void*)Sbr, 512, 128, 768,
      393216ll, 98304ll, 65536ll, 128ll, scale);
  hipLaunchKernelGGL(softmax128, dim3(8192), dim3(256), 0, stream, Sbr, Abr);
  // final: overwrites ALL of d_out (zb/ghb scratch dead from here)
  hipLaunchKernelGGL((gemm_nt64p<0, true>), dim3(6, 4, 64), dim3(256), 0, stream,
      Abr, memVoT, bvo, d_out, 512, 768, 128,
      65536ll, 98304ll, 393216ll, 0ll, 1.0f);
}

// Round 15
// 681.170 us; speedup vs baseline: 1.0170x; 1.0170x over previous
//
#include <hip/hip_runtime.h>
#include <hip/hip_bf16.h>
#include <math.h>

// Memory module: E=768, S=128, T=3, B=64, L=512. fp32 in/out.
// bf16 MFMA GEMMs (fp32 accum). Folds: Fqk=Wq^T Wk, Fwv=Wo Wv, Fvo=Ro Rv, Frq=Rq^T Rk.
// gemm_nt64 (BK=64, both-sides XOR swizzle, 32KB LDS) with LOOP-INVARIANT address
// hoisting (round-13 config: best measured, 685.6us). Round-14's counted-vmcnt
// double-buffer REGRESSED (occupancy 27->18%, FETCH +48%): reverted.
// d_out doubles as scratch: ghb at +0, zb at +48MB; final GEMM overwrites d_out last.

typedef __attribute__((ext_vector_type(4))) float f32x4;
typedef __attribute__((ext_vector_type(8))) short short8;
typedef __attribute__((ext_vector_type(4))) unsigned short us4;

__device__ __forceinline__ unsigned short f2bf(float x) {
  union { float f; unsigned u; } v; v.f = x;
  unsigned r = v.u + 0x7fffu + ((v.u >> 16) & 1u);  // RNE
  return (unsigned short)(r >> 16);
}
__device__ __forceinline__ float bf2f(unsigned short u) {
  union { unsigned u; float f; } v; v.u = (unsigned)u << 16; return v.f;
}

__device__ __forceinline__ void g2l16(const void* g, void* l) {
  __builtin_amdgcn_global_load_lds(
      (const __attribute__((address_space(1))) unsigned int*)g,
      (__attribute__((address_space(3))) unsigned int*)l, 16, 0, 0);
}

__device__ __forceinline__ float wsum(float v) {
#pragma unroll
  for (int o = 32; o > 0; o >>= 1) v += __shfl_xor(v, o, 64);
  return v;
}
__device__ __forceinline__ float wmax(float v) {
#pragma unroll
  for (int o = 32; o > 0; o >>= 1) v = fmaxf(v, __shfl_xor(v, o, 64));
  return v;
}

// m204 bijective XCD swizzle of flattened grid -> (tn, tm, bz)
__device__ __forceinline__ void xcd_map(int& tn, int& tm, long long& bz) {
  const int gx = gridDim.x, gy = gridDim.y, gz = gridDim.z;
  const int nwg = gx * gy * gz;
  const int lin = blockIdx.x + gx * (blockIdx.y + gy * blockIdx.z);
  const int q = nwg >> 3, r = nwg & 7;
  const int xcd = lin & 7, jj = lin >> 3;
  const int w = (xcd < r ? xcd * (q + 1) : r * (q + 1) + (xcd - r) * q) + jj;
  tn = w % gx;
  const int t2 = w / gx;
  tm = t2 % gy;
  bz = t2 / gy;
}

__device__ __forceinline__ void c_write_128(
    void* Cg, size_t cb, int N, int tm, int tn, int wr, int wc, int lane,
    const f32x4 acc[4][4], const float* bias, bool has_bias, float alpha, int omode)
{
#pragma unroll
  for (int a = 0; a < 4; ++a) {
    const int row0 = tm * 128 + wr * 64 + a * 16 + (lane >> 4) * 4;
#pragma unroll
    for (int b = 0; b < 4; ++b) {
      const int col = tn * 128 + wc * 64 + b * 16 + (lane & 15);
      float bv = has_bias ? bias[col] : 0.f;
#pragma unroll
      for (int rr = 0; rr < 4; ++rr) {
        float v = acc[a][b][rr] * alpha + bv;
        if (omode == 0)
          ((float*)Cg)[cb + (size_t)(row0 + rr) * N + col] = v;
        else
          ((unsigned short*)Cg)[cb + (size_t)(row0 + rr) * N + col] = f2bf(v);
      }
    }
  }
}

// ---- m97 128x128 BK=32 body (fold quad only) ----
template<int OMODE, bool BIAS>
__device__ __forceinline__ void gemm_body(
    const unsigned short* __restrict__ A, const unsigned short* __restrict__ B,
    const float* __restrict__ bias, void* __restrict__ Cg, size_t cb,
    int N, int K, int tm, int tn, float alpha,
    unsigned short* As, unsigned short* Bs)
{
  const int tid  = threadIdx.x;
  const int lane = tid & 63;
  const int wv   = tid >> 6;
  const int wr   = wv >> 1, wc = wv & 1;

  A += (size_t)tm * 128 * K;
  B += (size_t)tn * 128 * K;

  const int srow = wv * 16 + (lane >> 2);
  const int kby  = (lane & 3) * 16;

  f32x4 acc[4][4];
#pragma unroll
  for (int a = 0; a < 4; ++a)
#pragma unroll
    for (int b = 0; b < 4; ++b) acc[a][b] = (f32x4)(0.f);

  const int mrow = wr * 64 + (lane & 15);
  const int nrow = wc * 64 + (lane & 15);
  const int koff = (lane >> 4) * 8;

  for (int kt = 0; kt < K; kt += 32) {
#pragma unroll
    for (int i = 0; i < 2; ++i) {
      g2l16((const char*)(A + (size_t)(i * 64 + srow) * K + kt) + kby,
            (char*)As + i * 4096 + wv * 1024);
      g2l16((const char*)(B + (size_t)(i * 64 + srow) * K + kt) + kby,
            (char*)Bs + i * 4096 + wv * 1024);
    }
    __syncthreads();
    short8 af[4], bf[4];
#pragma unroll
    for (int a = 0; a < 4; ++a) af[a] = *(const short8*)&As[(mrow + a * 16) * 32 + koff];
#pragma unroll
    for (int b = 0; b < 4; ++b) bf[b] = *(const short8*)&Bs[(nrow + b * 16) * 32 + koff];
#pragma unroll
    for (int a = 0; a < 4; ++a)
#pragma unroll
      for (int b = 0; b < 4; ++b)
        acc[a][b] = __builtin_amdgcn_mfma_f32_16x16x32_bf16(af[a], bf[b], acc[a][b], 0, 0, 0);
    __syncthreads();
  }
  c_write_128(Cg, cb, N, tm, tn, wr, wc, lane, acc, bias, BIAS, alpha, OMODE);
}

// ---- BK=64 variant with hoisted addresses. 32KB LDS, XOR-swizzled (both sides).
// Requires K%64==0, M%128==0, N%128==0.
template<int OMODE, bool BIAS>
__global__ __launch_bounds__(256) void gemm_nt64(
    const unsigned short* __restrict__ Ag, const unsigned short* __restrict__ Bg,
    const float* __restrict__ bias, void* __restrict__ Cg,
    int M, int N, int K, long long sA, long long sB, long long sC,
    long long sBias, float alpha)
{
  __shared__ __align__(16) unsigned short As[128 * 64];  // 16KB
  __shared__ __align__(16) unsigned short Bs[128 * 64];

  const int tid  = threadIdx.x;
  const int lane = tid & 63;
  const int wv   = tid >> 6;
  const int wr   = wv >> 1, wc = wv & 1;

  int tn, tm; long long bz;
  xcd_map(tn, tm, bz);

  const unsigned short* A = Ag + bz * sA + (size_t)tm * 128 * K;
  const unsigned short* B = Bg + bz * sB + (size_t)tn * 128 * K;

  auto swz = [](int o) { return o ^ (((o >> 7) & 7) << 4); };

  // ---- loop-invariant staging source pointers (pre-swizzled global coords) ----
  const char* aSrc[4];
  const char* bSrc[4];
#pragma unroll
  for (int c = 0; c < 4; ++c) {
    const int olog = swz(c * 4096 + tid * 16);
    const int row = olog >> 7, cbyte = olog & 127;
    aSrc[c] = (const char*)(A + (size_t)row * K) + cbyte;
    bSrc[c] = (const char*)(B + (size_t)row * K) + cbyte;
  }
  // ---- loop-invariant LDS read byte-offsets (static-indexed -> registers) ----
  const int mrow = wr * 64 + (lane & 15);
  const int nrow = wc * 64 + (lane & 15);
  const int kb   = (lane >> 4) * 16;
  int aoff[4][2], boff[4][2];
#pragma unroll
  for (int a = 0; a < 4; ++a)
#pragma unroll
    for (int h = 0; h < 2; ++h) {
      aoff[a][h] = swz((mrow + a * 16) * 128 + h * 64 + kb);
      boff[a][h] = swz((nrow + a * 16) * 128 + h * 64 + kb);
    }

  f32x4 acc[4][4];
#pragma unroll
  for (int a = 0; a < 4; ++a)
#pragma unroll
    for (int b = 0; b < 4; ++b) acc[a][b] = (f32x4)(0.f);

  size_t ktB = 0;  // kt in bytes (64 bf16 = 128B per tile)
  for (int kt = 0; kt < K; kt += 64, ktB += 128) {
#pragma unroll
    for (int c = 0; c < 4; ++c) {
      g2l16(aSrc[c] + ktB, (char*)As + c * 4096 + wv * 1024);
      g2l16(bSrc[c] + ktB, (char*)Bs + c * 4096 + wv * 1024);
    }
    __syncthreads();
#pragma unroll
    for (int h = 0; h < 2; ++h) {
      short8 af[4], bf[4];
#pragma unroll
      for (int a = 0; a < 4; ++a)
        af[a] = *(const short8*)((char*)As + aoff[a][h]);
#pragma unroll
      for (int b = 0; b < 4; ++b)
        bf[b] = *(const short8*)((char*)Bs + boff[b][h]);
#pragma unroll
      for (int a = 0; a < 4; ++a)
#pragma unroll
        for (int b = 0; b < 4; ++b)
          acc[a][b] = __builtin_amdgcn_mfma_f32_16x16x32_bf16(af[a], bf[b], acc[a][b], 0, 0, 0);
    }
    __syncthreads();
  }

  const float* bp = BIAS ? bias + bz * sBias : (const float*)nullptr;
  c_write_128(Cg, (size_t)(bz * sC), N, tm, tn, wr, wc, lane, acc, bp, BIAS, alpha, OMODE);
}

// 4 independent 768^3 NT GEMMs (fold products). bf16 out, no bias.
struct QuadPtrs {
  const unsigned short* a[4];
  const unsigned short* b[4];
  unsigned short* c[4];
};
__global__ __launch_bounds__(256) void gemm_nt_quad(QuadPtrs p) {
  __shared__ __align__(16) unsigned short As[128 * 32];
  __shared__ __align__(16) unsigned short Bs[128 * 32];
  const int zi = blockIdx.z;
  gemm_body<1, false>(p.a[zi], p.b[zi], nullptr, (void*)p.c[zi], 0,
                      768, 768, blockIdx.y, blockIdx.x, 1.0f, As, Bs);
}

// Softmax LR=512: float4 loads, us4 stores. One wave per row.
__global__ __launch_bounds__(256) void softmax512(
    const float* __restrict__ sc, unsigned short* __restrict__ p)
{
  const int row  = blockIdx.x * 4 + (threadIdx.x >> 6);
  const int lane = threadIdx.x & 63;
  const float4* sr = (const float4*)(sc + (size_t)row * 512);
  float4 v[2];
  float m = -1e30f;
#pragma unroll
  for (int j = 0; j < 2; ++j) {
    v[j] = sr[lane + 64 * j];
    m = fmaxf(m, fmaxf(fmaxf(v[j].x, v[j].y), fmaxf(v[j].z, v[j].w)));
  }
  m = wmax(m);
  float s = 0.f;
#pragma unroll
  for (int j = 0; j < 2; ++j) {
    v[j].x = __expf(v[j].x - m); v[j].y = __expf(v[j].y - m);
    v[j].z = __expf(v[j].z - m); v[j].w = __expf(v[j].w - m);
    s += v[j].x + v[j].y + v[j].z + v[j].w;
  }
  s = wsum(s);
  const float inv = 1.f / s;
  us4* pr = (us4*)(p + (size_t)row * 512);
#pragma unroll
  for (int j = 0; j < 2; ++j) {
    us4 o;
    o.x = f2bf(v[j].x * inv); o.y = f2bf(v[j].y * inv);
    o.z = f2bf(v[j].z * inv); o.w = f2bf(v[j].w * inv);
    pr[lane + 64 * j] = o;
  }
}

// Softmax LR=128. One wave per row.
__global__ __launch_bounds__(256) void softmax128(
    const float* __restrict__ sc, unsigned short* __restrict__ p)
{
  const int row  = blockIdx.x * 4 + (threadIdx.x >> 6);
  const int lane = threadIdx.x & 63;
  const float* sr = sc + (size_t)row * 128;
  float v[2];
  float m = -1e30f;
#pragma unroll
  for (int j = 0; j < 2; ++j) { v[j] = sr[lane + 64 * j]; m = fmaxf(m, v[j]); }
  m = wmax(m);
  float s = 0.f;
#pragma unroll
  for (int j = 0; j < 2; ++j) { v[j] = __expf(v[j] - m); s += v[j]; }
  s = wsum(s);
  const float inv = 1.f / s;
  unsigned short* pr = p + (size_t)row * 128;
#pragma unroll
  for (int j = 0; j < 2; ++j) pr[lane + 64 * j] = f2bf(v[j] * inv);
}

// GRU combine with inline LN of old mem (h) + emit next operand.
template<bool GHB, bool EMITLN>
__global__ __launch_bounds__(256) void gru_ln_combine(
    const unsigned short* __restrict__ gi, const unsigned short* __restrict__ gh,
    float* __restrict__ mem, const float* __restrict__ g, const float* __restrict__ b,
    unsigned short* __restrict__ outb)
{
  __shared__ float ps[4], pq[4];
  const size_t row = blockIdx.x;
  const int tid = threadIdx.x, wv = tid >> 6, lane = tid & 63;
  float* mr = mem + row * 768;
  const size_t ghrow = GHB ? (row & 127) : row;
  float v[3];
  float s = 0.f, q = 0.f;
#pragma unroll
  for (int k = 0; k < 3; ++k) {
    v[k] = mr[tid + 256 * k];
    s += v[k]; q += v[k] * v[k];
  }
  s = wsum(s); q = wsum(q);
  if (lane == 0) { ps[wv] = s; pq[wv] = q; }
  __syncthreads();
  s = ps[0] + ps[1] + ps[2] + ps[3];
  q = pq[0] + pq[1] + pq[2] + pq[3];
  const float mu = s * (1.f / 768.f);
  const float rstd = rsqrtf(q * (1.f / 768.f) - mu * mu + 1e-5f);
  float nv[3];
  float s2 = 0.f, q2 = 0.f;
#pragma unroll
  for (int k = 0; k < 3; ++k) {
    const int c = tid + 256 * k;
    const float h = (v[k] - mu) * rstd * g[c] + b[c];
    const float ir  = bf2f(gi[row * 2304 + c]);
    const float iz  = bf2f(gi[row * 2304 + 768 + c]);
    const float in_ = bf2f(gi[row * 2304 + 1536 + c]);
    const float hr  = bf2f(gh[ghrow * 2304 + c]);
    const float hz  = bf2f(gh[ghrow * 2304 + 768 + c]);
    const float hn  = bf2f(gh[ghrow * 2304 + 1536 + c]);
    const float rg = 1.f / (1.f + __expf(-(ir + hr)));
    const float zg = 1.f / (1.f + __expf(-(iz + hz)));
    const float n  = tanhf(in_ + rg * hn);
    nv[k] = (1.f - zg) * n + zg * h;
    mr[c] = nv[k];
    s2 += nv[k]; q2 += nv[k] * nv[k];
  }
  if (EMITLN) {
    s2 = wsum(s2); q2 = wsum(q2);
    __syncthreads();
    if (lane == 0) { ps[wv] = s2; pq[wv] = q2; }
    __syncthreads();
    s2 = ps[0] + ps[1] + ps[2] + ps[3];
    q2 = pq[0] + pq[1] + pq[2] + pq[3];
    const float mu2 = s2 * (1.f / 768.f);
    const float rstd2 = rsqrtf(q2 * (1.f / 768.f) - mu2 * mu2 + 1e-5f);
#pragma unroll
    for (int k = 0; k < 3; ++k) {
      const int c = tid + 256 * k;
      outb[row * 768 + c] = f2bf((nv[k] - mu2) * rstd2 * g[c] + b[c]);
    }
  } else {
#pragma unroll
    for (int k = 0; k < 3; ++k) {
      const int c = tid + 256 * k;
      outb[row * 768 + c] = f2bf(nv[k]);
    }
  }
}

// Merged weight conversion: 10 fp32 sources -> contiguous bf16 region.
__global__ __launch_bounds__(256) void cvt_weights(
    const float* p0, const float* p1, const float* p2, const float* p3,
    const float* p4, const float* p5, const float* p6, const float* p7,
    const float* p8, const float* p9, unsigned short* __restrict__ dst)
{
  const int i = blockIdx.x * 256 + threadIdx.x;  // f4 index, total 2064384
  if (i >= 2064384) return;
  const float* src; int base;
  if      (i < 147456)  { src = p0; base = 0; }
  else if (i < 294912)  { src = p1; base = 147456; }
  else if (i < 442368)  { src = p2; base = 294912; }
  else if (i < 589824)  { src = p3; base = 442368; }
  else if (i < 737280)  { src = p4; base = 589824; }
  else if (i < 884736)  { src = p5; base = 737280; }
  else if (i < 1032192) { src = p6; base = 884736; }
  else if (i < 1179648) { src = p7; base = 1032192; }
  else if (i < 1622016) { src = p8; base = 1179648; }
  else                  { src = p9; base = 1622016; }
  const float4 v = ((const float4*)src)[i - base];
  us4 o;
  o.x = f2bf(v.x); o.y = f2bf(v.y); o.z = f2bf(v.z); o.w = f2bf(v.w);
  ((us4*)dst)[i] = o;
}

// memf[b,s,:] = slots[s,:]; memb[b,s,:] = bf16(LN(slots[s,:])). Grid (128, 8).
__global__ __launch_bounds__(256) void init_mem(
    const float* __restrict__ slots, const float* __restrict__ g,
    const float* __restrict__ b, float* __restrict__ memf,
    unsigned short* __restrict__ memb)
{
  __shared__ float ps[4], pq[4];
  const int s = blockIdx.x;
  const int g0 = blockIdx.y * 8;
  const int tid = threadIdx.x, wv = tid >> 6, lane = tid & 63;
  const float* sr = slots + (size_t)s * 768;
  float v[3];
  float su = 0.f, qu = 0.f;
#pragma unroll
  for (int k = 0; k < 3; ++k) { v[k] = sr[tid + 256 * k]; su += v[k]; qu += v[k] * v[k]; }
  su = wsum(su); qu = wsum(qu);
  if (lane == 0) { ps[wv] = su; pq[wv] = qu; }
  __syncthreads();
  su = ps[0] + ps[1] + ps[2] + ps[3];
  qu = pq[0] + pq[1] + pq[2] + pq[3];
  const float mu = su * (1.f / 768.f);
  const float rstd = rsqrtf(qu * (1.f / 768.f) - mu * mu + 1e-5f);
  unsigned short lb[3];
#pragma unroll
  for (int k = 0; k < 3; ++k) {
    const int c = tid + 256 * k;
    lb[k] = f2bf((v[k] - mu) * rstd * g[c] + b[c]);
  }
  for (int bb = g0; bb < g0 + 8; ++bb) {
    float* mrow = memf + ((size_t)bb * 128 + s) * 768;
    unsigned short* brow = memb + ((size_t)bb * 128 + s) * 768;
#pragma unroll
    for (int k = 0; k < 3; ++k) { mrow[tid + 256 * k] = v[k]; brow[tid + 256 * k] = lb[k]; }
  }
}

// 6 independent 768x768 transposes in one launch (weight prologue only).
struct TPtrs { const unsigned short* s[6]; unsigned short* d[6]; };
__global__ void transpose_multi(TPtrs p) {
  __shared__ unsigned short t[32][33];
  const unsigned short* in = p.s[blockIdx.z];
  unsigned short* out = p.d[blockIdx.z];
  const int c0 = blockIdx.x * 32, r0 = blockIdx.y * 32;
  const int x = threadIdx.x, y = threadIdx.y;
#pragma unroll
  for (int k = 0; k < 32; k += 8)
    t[y + k][x] = in[(size_t)(r0 + y + k) * 768 + c0 + x];
  __syncthreads();
#pragma unroll
  for (int k = 0; k < 32; k += 8)
    out[(size_t)(c0 + y + k) * 768 + r0 + x] = t[x][y + k];
}

// Two y[row] = dot(Tmat[row,:], x) jobs over bf16 row-major mats (wave per row).
__global__ __launch_bounds__(256) void matvec_row2b(
    const unsigned short* __restrict__ A0, const float* __restrict__ x0,
    float* __restrict__ y0,
    const unsigned short* __restrict__ A1, const float* __restrict__ x1,
    float* __restrict__ y1)
{
  const int task = blockIdx.x / 192;
  const int row = (blockIdx.x % 192) * 4 + (threadIdx.x >> 6);
  const int lane = threadIdx.x & 63;
  const unsigned short* r = (task ? A1 : A0) + (size_t)row * 768;
  const float* x = task ? x1 : x0;
  float s = 0.f;
#pragma unroll
  for (int j = 0; j < 12; ++j) s += bf2f(r[lane + 64 * j]) * x[lane + 64 * j];
  s = wsum(s);
  if (lane == 0) (task ? y1 : y0)[row] = s;
}

// Two y[row]=add[row]+dot(W[row,:],x) fp32 jobs (grid 384: task = bx/192).
__global__ __launch_bounds__(256) void matvec_row2(
    const float* __restrict__ W0, const float* __restrict__ x0,
    const float* __restrict__ a0, float* __restrict__ y0,
    const float* __restrict__ W1, const float* __restrict__ x1,
    const float* __restrict__ a1, float* __restrict__ y1)
{
  const int task = blockIdx.x / 192;
  const int row = (blockIdx.x % 192) * 4 + (threadIdx.x >> 6);
  const int lane = threadIdx.x & 63;
  const float* W = task ? W1 : W0;
  const float* x = task ? x1 : x0;
  const float* ad = task ? a1 : a0;
  float* y = task ? y1 : y0;
  const float4* r = (const float4*)(W + (size_t)row * 768);
  const float4* xv = (const float4*)x;
  float s = 0.f;
#pragma unroll
  for (int j = 0; j < 3; ++j) {
    const float4 a = r[lane + 64 * j], c = xv[lane + 64 * j];
    s += a.x * c.x + a.y * c.y + a.z * c.z + a.w * c.w;
  }
  s = wsum(s);
  if (lane == 0) y[row] = s + ad[row];
}

// out[i] = scl * (dot(src_i, vec) + (cadd ? cadd[0] : 0)). float4 loads.
__global__ __launch_bounds__(256) void rowdot768(
    const float* __restrict__ src, const float* __restrict__ vec,
    const float* __restrict__ cadd, float* __restrict__ out, float scl, int rows)
{
  const int row  = blockIdx.x * 4 + (threadIdx.x >> 6);
  if (row >= rows) return;
  const int lane = threadIdx.x & 63;
  const float4* r = (const float4*)(src + (size_t)row * 768);
  const float4* vv = (const float4*)vec;
  float s = 0.f;
#pragma unroll
  for (int j = 0; j < 3; ++j) {
    const float4 a = r[lane + 64 * j], c = vv[lane + 64 * j];
    s += a.x * c.x + a.y * c.y + a.z * c.z + a.w * c.w;
  }
  s = wsum(s);
  if (lane == 0) out[row] = scl * (s + (cadd ? cadd[0] : 0.f));
}

// Fused: zb = bf16(z) AND zv[row] = scl*(dot(z_row, vw) + cw[0]). float4 loads.
__global__ __launch_bounds__(256) void cvt_z_zv(
    const float* __restrict__ z, unsigned short* __restrict__ zb,
    const float* __restrict__ vw, const float* __restrict__ cw,
    float* __restrict__ zv, float scl)
{
  const int row = blockIdx.x * 4 + (threadIdx.x >> 6);
  const int lane = threadIdx.x & 63;
  const float4* zr = (const float4*)(z + (size_t)row * 768);
  const float4* wv = (const float4*)vw;
  us4* zbr = (us4*)(zb + (size_t)row * 768);
  float s = 0.f;
#pragma unroll
  for (int j = 0; j < 3; ++j) {
    const float4 v = zr[lane + 64 * j];
    const float4 w = wv[lane + 64 * j];
    s += v.x * w.x + v.y * w.y + v.z * w.z + v.w * w.w;
    us4 o;
    o.x = f2bf(v.x); o.y = f2bf(v.y); o.z = f2bf(v.z); o.w = f2bf(v.w);
    zbr[lane + 64 * j] = o;
  }
  s = wsum(s);
  if (lane == 0) zv[row] = scl * (s + cw[0]);
}

__global__ __launch_bounds__(256) void diag_ws(float* __restrict__ out, float wsz, int n) {
  const int i = blockIdx.x * 256 + threadIdx.x;
  if (i < n) out[i] = (i == 0) ? wsz : 0.f;
}

extern "C" void kernel_launch(void* const* d_in, const int* in_sizes, int n_in,
                              void* d_out, int out_size, void* d_ws, size_t ws_size,
                              hipStream_t stream)
{
  const float* z     = (const float*)d_in[0];
  const float* slots = (const float*)d_in[1];
  const float* ln_g  = (const float*)d_in[2];
  const float* ln_b  = (const float*)d_in[3];
  const float* w_wq = (const float*)d_in[4];  const float* w_bq = (const float*)d_in[5];
  const float* w_wk = (const float*)d_in[6];  const float* w_bk = (const float*)d_in[7];
  const float* w_wv = (const float*)d_in[8];  const float* w_bv = (const float*)d_in[9];
  const float* w_wo = (const float*)d_in[10]; const float* w_bo = (const float*)d_in[11];
  const float* r_wq = (const float*)d_in[12]; const float* r_bq = (const float*)d_in[13];
  const float* r_wk = (const float*)d_in[14]; const float* r_bk = (const float*)d_in[15];
  const float* r_wv = (const float*)d_in[16]; const float* r_bv = (const float*)d_in[17];
  const float* r_wo = (const float*)d_in[18]; const float* r_bo = (const float*)d_in[19];
  const float* g_wih = (const float*)d_in[20]; const float* g_bih = (const float*)d_in[21];
  const float* g_whh = (const float*)d_in[22]; const float* g_bhh = (const float*)d_in[23];

  // ---- arena (bytes) ----
  constexpr size_t O_F    = 16515072;
  constexpr size_t O_T6   = 21233664;
  constexpr size_t O_GH0  = 28311552;
  constexpr size_t O_FL   = 28901376;
  constexpr size_t O_memf = 29096192;
  constexpr size_t O_Kz   = 54262016;
  constexpr size_t O_VwoT = 104593664;
  constexpr size_t O_L    = 154925312;
  constexpr size_t NEED   = 217839872;

  if (ws_size < NEED) {
    hipLaunchKernelGGL(diag_ws, dim3((out_size + 255) / 256), dim3(256), 0, stream,
                       (float*)d_out, (float)ws_size, out_size);
    return;
  }

  char* ws = (char*)d_ws;
  unsigned short* wqb  = (unsigned short*)(ws + 0);
  unsigned short* wkb  = wqb + 589824;
  unsigned short* wvb  = wkb + 589824;
  unsigned short* wob  = wvb + 589824;
  unsigned short* rqb  = wob + 589824;
  unsigned short* rkb  = rqb + 589824;
  unsigned short* rvb  = rkb + 589824;
  unsigned short* rob  = rvb + 589824;
  unsigned short* wihb = rob + 589824;
  unsigned short* whhb = wihb + 1769472;
  unsigned short* Fqk  = (unsigned short*)(ws + O_F);
  unsigned short* Fwv  = Fqk + 589824;
  unsigned short* Fvo  = Fwv + 589824;
  unsigned short* Frq  = Fvo + 589824;
  unsigned short* T0   = (unsigned short*)(ws + O_T6);
  unsigned short* T1   = T0 + 589824;
  unsigned short* T2   = T1 + 589824;
  unsigned short* T3   = T2 + 589824;
  unsigned short* T4   = T3 + 589824;
  unsigned short* T5   = T4 + 589824;
  unsigned short* gh0  = (unsigned short*)(ws + O_GH0);
  float* bih_c   = (float*)(ws + O_FL);
  float* bhh_c   = bih_c + 2304;
  float* const_o = bhh_c + 2304;
  float* bvo     = const_o + 768;
  float* vw      = bvo + 768;
  float* vr      = vw + 768;
  float* cw      = vr + 768;
  float* zv      = cw + 64;
  float* colb    = zv + 32768;
  float* memf = (float*)(ws + O_memf);
  unsigned short* Kz    = (unsigned short*)(ws + O_Kz);
  unsigned short* memFr = (unsigned short*)(ws + O_Kz);            // end (Kz dead)
  unsigned short* VwoT  = (unsigned short*)(ws + O_VwoT);
  unsigned short* memVoT  = (unsigned short*)(ws + O_VwoT);             // end
  float*          Sbr     = (float*)(ws + O_VwoT + 25165824);           // end
  unsigned short* Abr     = (unsigned short*)(ws + O_VwoT + 41943040);  // end
  char* L = ws + O_L;
  unsigned short* memb  = (unsigned short*)(L + 0);
  unsigned short* updb  = (unsigned short*)(L + 12582912);
  float*          Sbuf  = (float*)(L + 25165824);
  unsigned short* Abuf  = (unsigned short*)(L + 41943040);
  unsigned short* gib   = (unsigned short*)(L + 25165824);   // (S/A dead)
  unsigned short* ghb   = (unsigned short*)d_out;
  unsigned short* zb    = (unsigned short*)((char*)d_out + 50331648);

  const float scale = 1.0f / sqrtf(768.f);

  // ---- prologue ----
  hipLaunchKernelGGL(cvt_weights, dim3(8064), dim3(256), 0, stream,
      w_wq, w_wk, w_wv, w_wo, r_wq, r_wk, r_wv, r_wo, g_wih, g_whh, wqb);
  hipMemcpyAsync(bih_c, g_bih, 2304 * 4, hipMemcpyDeviceToDevice, stream);
  hipMemcpyAsync(bhh_c, g_bhh, 2304 * 4, hipMemcpyDeviceToDevice, stream);

  {
    TPtrs tp;
    tp.s[0] = wqb; tp.d[0] = T0;
    tp.s[1] = wkb; tp.d[1] = T1;
    tp.s[2] = wvb; tp.d[2] = T2;
    tp.s[3] = rvb; tp.d[3] = T3;
    tp.s[4] = rqb; tp.d[4] = T4;
    tp.s[5] = rkb; tp.d[5] = T5;
    hipLaunchKernelGGL(transpose_multi, dim3(24, 24, 6), dim3(32, 8), 0, stream, tp);
  }
  {
    QuadPtrs qp;
    qp.a[0] = T0;  qp.b[0] = T1; qp.c[0] = Fqk;
    qp.a[1] = wob; qp.b[1] = T2; qp.c[1] = Fwv;
    qp.a[2] = rob; qp.b[2] = T3; qp.c[2] = Fvo;
    qp.a[3] = T4;  qp.b[3] = T5; qp.c[3] = Frq;
    hipLaunchKernelGGL(gemm_nt_quad, dim3(6, 6, 4), dim3(256), 0, stream, qp);
  }

  hipLaunchKernelGGL(matvec_row2b, dim3(384), dim3(256), 0, stream,
      T1, w_bq, vw, T5, r_bq, vr);
  hipLaunchKernelGGL(matvec_row2, dim3(384), dim3(256), 0, stream,
      w_wo, w_bv, w_bo, const_o, r_wo, r_bv, r_bo, bvo);
  hipLaunchKernelGGL(rowdot768, dim3(1), dim3(256), 0, stream,
      w_bq, w_bk, (const float*)nullptr, cw, 1.0f, 1);
  hipLaunchKernelGGL(cvt_z_zv, dim3(8192), dim3(256), 0, stream, z, zb, vw, cw, zv, scale);
  hipLaunchKernelGGL(init_mem, dim3(128, 8), dim3(256), 0, stream,
      slots, ln_g, ln_b, memf, memb);

  // VwoT[b] = Fwv . z_b^T ; Kz = z . Fqk^T
  hipLaunchKernelGGL((gemm_nt64<1, false>), dim3(4, 6, 64), dim3(256), 0, stream,
      Fwv, zb, (const float*)nullptr, (void*)VwoT, 768, 512, 768,
      0ll, 393216ll, 393216ll, 0ll, 1.0f);
  hipLaunchKernelGGL((gemm_nt64<1, false>), dim3(6, 256, 1), dim3(256), 0, stream,
      zb, Fqk, (const float*)nullptr, (void*)Kz, 32768, 768, 768, 0ll, 0ll, 0ll, 0ll, 1.0f);

  const long long sA_g = (long long)(memb - updb);
  const long long sC_g = (long long)(ghb - gib);

  // ---- T=3 recurrence ----
  for (int t = 0; t < 3; ++t) {
    hipLaunchKernelGGL((gemm_nt64<0, true>), dim3(4, 1, 64), dim3(256), 0, stream,
        memb, Kz, zv, (void*)Sbuf, 128, 512, 768,
        98304ll, 393216ll, 65536ll, 512ll, scale);
    hipLaunchKernelGGL(softmax512, dim3(2048), dim3(256), 0, stream, Sbuf, Abuf);
    hipLaunchKernelGGL((gemm_nt64<1, true>), dim3(6, 1, 64), dim3(256), 0, stream,
        Abuf, VwoT, const_o, (void*)updb, 128, 768, 512,
        65536ll, 393216ll, 98304ll, 0ll, 1.0f);
    if (t == 0) {
      hipLaunchKernelGGL((gemm_nt64<1, true>), dim3(18, 1, 1), dim3(256), 0, stream,
          memb, whhb, bhh_c, (void*)gh0, 128, 2304, 768, 0ll, 0ll, 0ll, 0ll, 1.0f);
      hipLaunchKernelGGL((gemm_nt64<1, true>), dim3(18, 64, 1), dim3(256), 0, stream,
          updb, wihb, bih_c, (void*)gib, 8192, 2304, 768, 0ll, 0ll, 0ll, 0ll, 1.0f);
      hipLaunchKernelGGL((gru_ln_combine<true, true>), dim3(8192), dim3(256), 0, stream,
          gib, gh0, memf, ln_g, ln_b, memb);
    } else {
      hipLaunchKernelGGL((gemm_nt64<1, true>), dim3(18, 64, 2), dim3(256), 0, stream,
          updb, wihb, bih_c, (void*)gib, 8192, 2304, 768,
          sA_g, 1769472ll, sC_g, 2304ll, 1.0f);
      if (t < 2)
        hipLaunchKernelGGL((gru_ln_combine<false, true>), dim3(8192), dim3(256), 0, stream,
            gib, ghb, memf, ln_g, ln_b, memb);
      else
        hipLaunchKernelGGL((gru_ln_combine<false, false>), dim3(8192), dim3(256), 0, stream,
            gib, ghb, memf, ln_g, ln_b, memb);
    }
  }
  // memb now holds bf16(mem_final)

  // ---- read attention ----
  hipLaunchKernelGGL((gemm_nt64<1, false>), dim3(6, 64, 1), dim3(256), 0, stream,
      memb, Frq, (const float*)nullptr, (void*)memFr, 8192, 768, 768,
      0ll, 0ll, 0ll, 0ll, 1.0f);
  hipLaunchKernelGGL((gemm_nt64<1, false>), dim3(1, 6, 64), dim3(256), 0, stream,
      Fvo, memb, (const float*)nullptr, (void*)memVoT, 768, 128, 768,
      0ll, 98304ll, 98304ll, 0ll, 1.0f);
  hipLaunchKernelGGL(rowdot768, dim3(2048), dim3(256), 0, stream,
      memf, vr, (const float*)nullptr, colb, scale, 8192);
  hipLaunchKernelGGL((gemm_nt64<0, true>), dim3(1, 4, 64), dim3(256), 0, stream,
      zb, memFr, colb, (void*)Sbr, 512, 128, 768,
      393216ll, 98304ll, 65536ll, 128ll, scale);
  hipLaunchKernelGGL(softmax128, dim3(8192), dim3(256), 0, stream, Sbr, Abr);
  // final: overwrites ALL of d_out (zb/ghb scratch dead from here)
  hipLaunchKernelGGL((gemm_nt64<0, true>), dim3(6, 4, 64), dim3(256), 0, stream,
      Abr, memVoT, bvo, d_out, 512, 768, 128,
      65536ll, 98304ll, 393216ll, 0ll, 1.0f);
}